// Round 7
// baseline (35092.508 us; speedup 1.0000x reference)
//
#include <hip/hip_runtime.h>
#include <hip/hip_bf16.h>
#include <cstdint>

// ---------------------------------------------------------------------------
// SsLayer: outputs[2,B,T,OUT] (loc, softplus-scale) + state_out[B,NS]
// Plan:
//   ck_* : fp32 -> f16 conversions / layout prep (x, Bm^T, [C|D]^T, A scan layout)
//   gemm<256,0>: U = x @ Bm + b            (f16 MFMA, out f16 in ws)
//   scan       : s_{t+1} = tanh(u_t + s_t A), DISTRIBUTED: 256 WGs (1/CU),
//                4 WGs per batch, each owns 128 output columns with its
//                512x128 A-slice LDS-RESIDENT (128 KB). Per step: LDS-fed
//                dot products -> per-slice state written to S16 row ->
//                threadfence + agent-scope flag -> partners spin -> re-read
//                full 1 KB state row with agent-scope (L1-bypass) loads.
//                Rationale: rounds 0-6 proved one CU cannot move 512 KB of
//                A per step (L1 ~110 B/cyc best; VGPR residency unreachable:
//                plain loads sink (R0/R1/R4), pin constructs fail (R2/R3)).
//                Distributing A 4-ways puts it on 4 LDS ports.
//   gemm<512,1>: loc = S@C + c ; scale = softplus(S@D + d)  (fp32 out)
// ---------------------------------------------------------------------------

typedef _Float16 f16;
typedef _Float16 f16x2 __attribute__((ext_vector_type(2)));
typedef _Float16 f16x4 __attribute__((ext_vector_type(4)));
typedef _Float16 f16x8 __attribute__((ext_vector_type(8)));
typedef float    f32x4 __attribute__((ext_vector_type(4)));

#define NS 512

// ws byte offsets (total exactly 135,528,448 B = the PROVEN round-0/4
// footprint; do not exceed). x16 shares the S16 region: x16 is dead after
// gemm1; scan then overwrites the region with S16. Flags live in the first
// 1 KB of the BmT region (dead after gemm1), zeroed by ck_zero pre-scan.
#define OFF_S16   (0ull)            // 67,108,864   (S: [B*T, 512] f16)
#define OFF_X16   (0ull)            // 33,554,432   (x16 lives here during phase 1)
#define OFF_U16   (67108864ull)     // 67,108,864   (U: [B*T, 512] f16, bias added)
#define OFF_BMT   (134217728ull)    //    262,144   (Bm^T: [512][256] f16; +flags after gemm1)
#define OFF_CDT   (134479872ull)    //    524,288   ([C|D]^T: [512][512] f16)
#define OFF_AL    (135004160ull)    //    524,288   (A slices: [q][qd][t] packed quads)
                                    // end = 135,528,448

#if defined(__has_builtin)
#  if __has_builtin(__builtin_amdgcn_fdot2)
#    define HAS_FDOT2 1
#  endif
#endif

__device__ __forceinline__ float fdot2f(unsigned a, unsigned s, float c) {
#ifdef HAS_FDOT2
  return __builtin_amdgcn_fdot2(__builtin_bit_cast(f16x2, a),
                                __builtin_bit_cast(f16x2, s), c, false);
#else
  f16x2 av = __builtin_bit_cast(f16x2, a);
  f16x2 sv = __builtin_bit_cast(f16x2, s);
  return c + (float)av[0] * (float)sv[0] + (float)av[1] * (float)sv[1];
#endif
}

__device__ __forceinline__ unsigned packh2(float a, float b) {
  f16x2 h; h[0] = (f16)a; h[1] = (f16)b;
  return __builtin_bit_cast(unsigned, h);
}

// ------------------------------ prep kernels -------------------------------

__global__ void ck_x(const float* __restrict__ xg, f16* __restrict__ x16) {
  int i = (blockIdx.x * 256 + threadIdx.x) * 4;
  float4 v = *(const float4*)(xg + i);
  f16x4 h; h[0] = (f16)v.x; h[1] = (f16)v.y; h[2] = (f16)v.z; h[3] = (f16)v.w;
  *(f16x4*)(x16 + i) = h;
}

__global__ void ck_bmt(const float* __restrict__ Bm, f16* __restrict__ BmT) {
  int g = blockIdx.x * 256 + threadIdx.x;   // 131072 = 512*256
  int n = g >> 8, k = g & 255;
  BmT[g] = (f16)Bm[k * 512 + n];            // BmT[n][k]
}

__global__ void ck_cdt(const float* __restrict__ C, const float* __restrict__ D,
                       f16* __restrict__ CDT) {
  int g = blockIdx.x * 256 + threadIdx.x;   // 262144 = 512*512
  int n = g >> 9, k = g & 511;
  float v = (n < 256) ? C[k * 256 + n] : D[k * 256 + (n - 256)];
  CDT[g] = (f16)v;                          // CDT[n][k], n<256 -> C, else D
}

// A scan layout (distributed). Slice q owns columns q*128..q*128+127.
// Scan thread t of slice q: kb = t>>6 (8 k-blocks of 64 rows = 32 pairs),
// l = t&63; its 2 columns are j = q*128 + jj*64 + l (jj = 0,1).
// Quad (q, qd=pq*2+jj, t), dword d: pair p = pq*4 + d,
//   value = pack(A[kb*64+2p][j], A[kb*64+2p+1][j]).
// Linear: AL4[(q*16 + qd)*512 + t]  (lane-consecutive, conflict-free b128)
__global__ void ck_a(const float* __restrict__ Ag, unsigned* __restrict__ AL) {
  int g = blockIdx.x * 256 + threadIdx.x;   // 131072 packed dwords total
  int F = g >> 2, d = g & 3;
  int t = F & 511, qq = F >> 9;             // qq = 0..63
  int q = qq >> 4, qd = qq & 15;
  int pq = qd >> 1, jj = qd & 1;
  int p = pq * 4 + d;
  int kb = t >> 6, l = t & 63;
  int k0 = kb * 64 + 2 * p;
  int j = q * 128 + jj * 64 + l;
  AL[g] = packh2(Ag[k0 * 512 + j], Ag[(k0 + 1) * 512 + j]);
}

__global__ void ck_zero(int* __restrict__ flags) {
  flags[threadIdx.x] = 0;                   // 256 ints: [batch][quarter]
}

// ------------------------------- GEMM --------------------------------------
// C[M,128-tile] = A[M,K] @ B  with B given transposed: Bt[n][k].
// Block 256 thr = 4 waves, each wave a 64x64 quadrant, 16x16x32 f16 MFMA.
// MODE 0: out f16 = val + bias0[n]   (U)
// MODE 1: n<256 -> loc = val + bias0[n] ; else scale = softplus(val + bias1[n-256])
template <int KDIM, int MODE>
__global__ __launch_bounds__(256, 2) void gemm_kernel(
    const f16* __restrict__ Ag, const f16* __restrict__ Bt,
    const float* __restrict__ bias0, const float* __restrict__ bias1,
    void* __restrict__ outp) {
  __shared__ f16 At[128 * 40];   // 32 k + 8 pad per row (bank-conflict-free b128)
  __shared__ f16 Bs[128 * 40];
  const int tid = threadIdx.x;
  const int m0 = blockIdx.y * 128;
  const int n0 = blockIdx.x * 128;
  const int w = tid >> 6, lane = tid & 63;
  const int wm = w & 1, wn = w >> 1;
  const int r = lane & 15, qd = lane >> 4;

  f32x4 zero4 = {0.f, 0.f, 0.f, 0.f};
  f32x4 acc[4][4];
#pragma unroll
  for (int mt = 0; mt < 4; ++mt)
#pragma unroll
    for (int nt = 0; nt < 4; ++nt) acc[mt][nt] = zero4;

  for (int kk = 0; kk < KDIM; kk += 32) {
#pragma unroll
    for (int s = 0; s < 2; ++s) {
      int fi = tid * 2 + s;
      int row = fi >> 2, q = fi & 3;
      float4 av = *(const float4*)(Ag + (size_t)(m0 + row) * KDIM + kk + q * 8);
      *(float4*)(At + row * 40 + q * 8) = av;
      float4 bv = *(const float4*)(Bt + (size_t)(n0 + row) * KDIM + kk + q * 8);
      *(float4*)(Bs + row * 40 + q * 8) = bv;
    }
    __syncthreads();
    f16x8 af[4], bf[4];
#pragma unroll
    for (int mt = 0; mt < 4; ++mt)
      af[mt] = *(const f16x8*)(At + (wm * 64 + mt * 16 + r) * 40 + qd * 8);
#pragma unroll
    for (int nt = 0; nt < 4; ++nt)
      bf[nt] = *(const f16x8*)(Bs + (wn * 64 + nt * 16 + r) * 40 + qd * 8);
#pragma unroll
    for (int mt = 0; mt < 4; ++mt)
#pragma unroll
      for (int nt = 0; nt < 4; ++nt)
        acc[mt][nt] = __builtin_amdgcn_mfma_f32_16x16x32_f16(af[mt], bf[nt],
                                                             acc[mt][nt], 0, 0, 0);
    __syncthreads();
  }

#pragma unroll
  for (int mt = 0; mt < 4; ++mt) {
#pragma unroll
    for (int nt = 0; nt < 4; ++nt) {
      int n = n0 + wn * 64 + nt * 16 + r;
#pragma unroll
      for (int i = 0; i < 4; ++i) {
        int m = m0 + wm * 64 + mt * 16 + qd * 4 + i;
        float v = acc[mt][nt][i];
        if (MODE == 0) {
          ((f16*)outp)[(size_t)m * NS + n] = (f16)(v + bias0[n]);
        } else {
          if (n < 256) {
            ((float*)outp)[(size_t)m * 256 + n] = v + bias0[n];
          } else {
            float z = v + bias1[n - 256];
            float sp = (z > 20.f) ? z : log1pf(__expf(z));
            ((float*)outp)[16777216ull + (size_t)m * 256 + (n - 256)] = sp;
          }
        }
      }
    }
  }
}

// ------------------------------- scan --------------------------------------

#define BCU(x) __builtin_bit_cast(unsigned, (x))

__global__ __launch_bounds__(512, 1) void scan_kernel(
    const float4* __restrict__ AL4, const f16* __restrict__ U16,
    f16* __restrict__ S16, float* __restrict__ stout, int* flags) {
  __shared__ __align__(16) f16 ldsA[65536];   // A slice, 128 KB, [qd][t] quads
  __shared__ float part[1024];                // [kb 0..7][j_local 0..127], 4 KB
  __shared__ __align__(16) f16 sh[512];       // full state (read as float4)
  const int t = threadIdx.x;
  const int bid = blockIdx.x;
  const int q = bid >> 6;       // column-quarter; partners share bid%64 ->
  const int b = bid & 63;       // same XCD under round-robin (locality only)
  const int kb = t >> 6, l = t & 63;

  // A slice -> LDS: thread t copies exactly the 16 quads it will read
  float4* ldsA4 = (float4*)ldsA;
#pragma unroll
  for (int qd = 0; qd < 16; ++qd)
    ldsA4[qd * 512 + t] = AL4[(q * 16 + qd) * 512 + t];

  sh[t] = (f16)0.f;                           // s_0 = 0
  __syncthreads();
  const float4* sp4 = (const float4*)sh;

#pragma unroll 1
  for (int ts = 0; ts < 1024; ++ts) {
    const int row = b * 1024 + ts;
    f16 uh = (f16)0.f;
    if (t < 128) uh = U16[(size_t)row * 512 + q * 128 + t];  // issued early

    // s_t . A[:, my 2 columns]: 32 pairs, all from LDS (port parallel to L1)
    float acc0 = 0.f, acc1 = 0.f;
#pragma unroll
    for (int pq = 0; pq < 8; ++pq) {
      float4 s4 = sp4[kb * 8 + pq];           // wave-uniform broadcast (kb==wave)
      float4 A0 = ldsA4[(pq * 2 + 0) * 512 + t];   // col jj=0, pairs pq*4..+3
      float4 A1 = ldsA4[(pq * 2 + 1) * 512 + t];   // col jj=1
      acc0 = fdot2f(BCU(A0.x), BCU(s4.x), acc0);
      acc0 = fdot2f(BCU(A0.y), BCU(s4.y), acc0);
      acc0 = fdot2f(BCU(A0.z), BCU(s4.z), acc0);
      acc0 = fdot2f(BCU(A0.w), BCU(s4.w), acc0);
      acc1 = fdot2f(BCU(A1.x), BCU(s4.x), acc1);
      acc1 = fdot2f(BCU(A1.y), BCU(s4.y), acc1);
      acc1 = fdot2f(BCU(A1.z), BCU(s4.z), acc1);
      acc1 = fdot2f(BCU(A1.w), BCU(s4.w), acc1);
    }

    // partials: lanes write consecutive dwords (conflict-free)
    part[kb * 128 + l] = acc0;          // j_local = l
    part[kb * 128 + 64 + l] = acc1;     // j_local = 64 + l
    __syncthreads();

    // reduce over k-blocks for j_local = t, add u, tanh (threads 0..127)
    if (t < 128) {
      float sum = (float)uh;
#pragma unroll
      for (int k2 = 0; k2 < 8; ++k2) sum += part[k2 * 128 + t];
      float e = __expf(2.f * sum);
      float ns = 1.f - 2.f / (e + 1.f);                // tanh(sum)
      S16[(size_t)row * 512 + q * 128 + t] = (f16)ns;  // slice of the exchange row
      if (ts == 1022) stout[(size_t)b * 512 + q * 128 + t] = ns;
    }

    if (ts < 1023) {
      __threadfence();      // flush slice stores to the coherence point
      __syncthreads();      // all writers fenced before the flag releases
      if (t == 0)
        __hip_atomic_store(&flags[(b << 2) | q], ts + 1,
                           __ATOMIC_RELEASE, __HIP_MEMORY_SCOPE_AGENT);
      if (t < 4) {
        // own flag already set before any spin -> no circular wait
        int spins = 0;
        while (__hip_atomic_load(&flags[(b << 2) | t], __ATOMIC_ACQUIRE,
                                 __HIP_MEMORY_SCOPE_AGENT) <= ts) {
          __builtin_amdgcn_s_sleep(1);
          if (++spins > (1 << 14)) break;  // pathology -> visible failure, not a hang
        }
      }
      __syncthreads();
      // re-read the full 1 KB state row, L1-bypassing (agent-scope) loads
      if (t < 256) {
        unsigned v = __hip_atomic_load((unsigned*)S16 + (size_t)row * 256 + t,
                                       __ATOMIC_RELAXED, __HIP_MEMORY_SCOPE_AGENT);
        ((unsigned*)sh)[t] = v;
      }
      __syncthreads();
    }
  }
}

// ------------------------------ launcher -----------------------------------

extern "C" void kernel_launch(void* const* d_in, const int* in_sizes, int n_in,
                              void* d_out, int out_size, void* d_ws, size_t ws_size,
                              hipStream_t stream) {
  (void)in_sizes; (void)n_in; (void)out_size; (void)ws_size;
  const float* xg  = (const float*)d_in[0];
  const float* Ag  = (const float*)d_in[1];
  const float* Bmg = (const float*)d_in[2];
  const float* bg  = (const float*)d_in[3];
  const float* Cg  = (const float*)d_in[4];
  const float* cg  = (const float*)d_in[5];
  const float* Dg  = (const float*)d_in[6];
  const float* dg  = (const float*)d_in[7];

  char* w = (char*)d_ws;
  f16* x16 = (f16*)(w + OFF_X16);
  f16* U16 = (f16*)(w + OFF_U16);
  f16* S16 = (f16*)(w + OFF_S16);
  f16* BmT = (f16*)(w + OFF_BMT);
  f16* CDT = (f16*)(w + OFF_CDT);
  unsigned* AL = (unsigned*)(w + OFF_AL);
  int* flags = (int*)(w + OFF_BMT);     // first 1 KB of BmT, dead after gemm1
  float* out = (float*)d_out;

  ck_x  <<<16384, 256, 0, stream>>>(xg, x16);
  ck_bmt<<<  512, 256, 0, stream>>>(Bmg, BmT);
  ck_cdt<<< 1024, 256, 0, stream>>>(Cg, Dg, CDT);
  ck_a  <<<  512, 256, 0, stream>>>(Ag, AL);

  // U = x @ Bm + b
  gemm_kernel<256, 0><<<dim3(4, 512), 256, 0, stream>>>(x16, BmT, bg, nullptr,
                                                        (void*)U16);
  // flags must be zeroed after gemm1 (they alias BmT) and before the scan
  ck_zero<<<1, 256, 0, stream>>>(flags);
  // distributed sequential scan (overwrites x16 region with S16)
  scan_kernel<<<256, 512, 0, stream>>>((const float4*)AL, U16, S16,
                                       out + 33554432, flags);
  // loc / softplus(scale) from S
  gemm_kernel<512, 1><<<dim3(4, 512), 256, 0, stream>>>(S16, CDT, cg, dg,
                                                        (void*)out);
}